// Round 1
// baseline (197.805 us; speedup 1.0000x reference)
//
#include <hip/hip_runtime.h>

typedef __attribute__((ext_vector_type(8))) short short8;
typedef __attribute__((ext_vector_type(4))) float f32x4;

#define NHEADS 12
#define SEQLEN 2048
#define HEADD  64
#define DMODEL 768

// f32 -> bf16 round-to-nearest-even
__device__ __forceinline__ short cvtbf(float f) {
  unsigned u = __builtin_bit_cast(unsigned, f);
  u += 0x7fffu + ((u >> 16) & 1u);
  return (short)(u >> 16);
}

// async global->LDS, 16B per lane; lds base must be wave-uniform (HW adds lane*16)
__device__ __forceinline__ void gload16(const void* g, void* l) {
  __builtin_amdgcn_global_load_lds((const __attribute__((address_space(1))) void*)g,
                                   (__attribute__((address_space(3))) void*)l, 16, 0, 0);
}

// ---------------- kernel 1: cast x (4096x768 f32) -> bf16 ----------------
__global__ void cvt_x_kernel(const float* __restrict__ x, short* __restrict__ o) {
  int i = blockIdx.x * 256 + threadIdx.x;     // 1536 blocks * 256 * 8 = 3145728
  const float* p = x + (size_t)i * 8;
  short8 v;
#pragma unroll
  for (int j = 0; j < 8; ++j) v[j] = cvtbf(p[j]);
  *(short8*)(o + (size_t)i * 8) = v;
}

// ------------- kernel 2: transpose+cast weights to bf16 [n][k] -------------
__global__ void transpose_w_kernel(const float* __restrict__ w0, const float* __restrict__ w1,
                                   const float* __restrict__ w2, const float* __restrict__ w3,
                                   short* __restrict__ wt, short* __restrict__ wot) {
  __shared__ float t[32][33];
  const float* W = blockIdx.z == 0 ? w0 : blockIdx.z == 1 ? w1 : blockIdx.z == 2 ? w2 : w3;
  short* O = blockIdx.z < 3 ? wt + (size_t)blockIdx.z * (768 * 768) : wot;
  int tx = threadIdx.x, ty = threadIdx.y;      // (32,8)
  int n0 = blockIdx.x * 32, k0 = blockIdx.y * 32;
#pragma unroll
  for (int j = 0; j < 4; ++j)
    t[ty + j * 8][tx] = W[(k0 + ty + j * 8) * 768 + n0 + tx];
  __syncthreads();
#pragma unroll
  for (int j = 0; j < 4; ++j)
    O[(n0 + ty + j * 8) * 768 + k0 + tx] = cvtbf(t[tx][ty + j * 8]);
}

// ---------------- shared GEMM core: C[128x128] = A[128xK] * Bt[nxK]^T ----------------
// A: [4096][768] bf16 row-major (k contig). Bt: [N][768] bf16 (k contig).
// LDS tiles BK=64, XOR swizzle c' = c ^ (r&7) at 16B-chunk granularity.
__device__ __forceinline__ void gemm_core(const short* __restrict__ A,
                                          const short* __restrict__ Bt,
                                          short* sA, short* sB,
                                          int bm, int bn, f32x4 acc[4][4]) {
  const int tid = threadIdx.x;
  const int w = tid >> 6, lane = tid & 63;
  const int quad = lane >> 4, l16 = lane & 15;
  const int wm = (w & 1) << 6, wn = (w >> 1) << 6;

  int gA[4], gB[4], lbase[4];
#pragma unroll
  for (int j = 0; j < 4; ++j) {
    int slot = w * 256 + j * 64 + lane;        // 1024 16B chunks per tile
    int r = slot >> 3;
    int c = (slot & 7) ^ (r & 7);
    gA[j] = (bm * 128 + r) * 768 + c * 8;
    gB[j] = (bn * 128 + r) * 768 + c * 8;
    lbase[j] = (w * 256 + j * 64) * 8;         // shorts; wave-uniform
  }

  for (int kt = 0; kt < 12; ++kt) {
    __syncthreads();
#pragma unroll
    for (int j = 0; j < 4; ++j) {
      gload16(A + gA[j] + kt * 64, sA + lbase[j]);
      gload16(Bt + gB[j] + kt * 64, sB + lbase[j]);
    }
    __syncthreads();
#pragma unroll
    for (int ks = 0; ks < 2; ++ks) {
      short8 a[4], b[4];
#pragma unroll
      for (int mt = 0; mt < 4; ++mt) {
        int row = wm + mt * 16 + l16;
        int cp = (ks * 4 + quad) ^ (l16 & 7);
        a[mt] = *(const short8*)(sA + row * 64 + cp * 8);
      }
#pragma unroll
      for (int nt = 0; nt < 4; ++nt) {
        int row = wn + nt * 16 + l16;
        int cp = (ks * 4 + quad) ^ (l16 & 7);
        b[nt] = *(const short8*)(sB + row * 64 + cp * 8);
      }
#pragma unroll
      for (int mt = 0; mt < 4; ++mt)
#pragma unroll
        for (int nt = 0; nt < 4; ++nt)
          acc[mt][nt] = __builtin_amdgcn_mfma_f32_16x16x32_bf16(a[mt], b[nt], acc[mt][nt], 0, 0, 0);
    }
  }
}

// ---------------- kernel 3: fused QKV projection ----------------
// grid (32, 18): bn/6 selects segment (0=Q,1=K,2=V), writes bf16:
//  Q,K -> [b][h][s][64]; V -> [b][h][64][s] (transposed for PV B-operand)
__global__ __launch_bounds__(256, 2) void qkv_gemm(
    const short* __restrict__ A, const short* __restrict__ Bt,
    const float* __restrict__ bq, const float* __restrict__ bk, const float* __restrict__ bv,
    short* __restrict__ oq, short* __restrict__ ok, short* __restrict__ ov) {
  __shared__ short sA[128 * 64];
  __shared__ short sB[128 * 64];
  f32x4 acc[4][4];
  const f32x4 z4 = {0.f, 0.f, 0.f, 0.f};
#pragma unroll
  for (int mt = 0; mt < 4; ++mt)
#pragma unroll
    for (int nt = 0; nt < 4; ++nt) acc[mt][nt] = z4;

  const int bm = blockIdx.x, bn = blockIdx.y;
  gemm_core(A, Bt, sA, sB, bm, bn, acc);

  const int seg = bn / 6, bn_l = bn % 6;
  const float* bias = seg == 0 ? bq : seg == 1 ? bk : bv;
  short* outp = seg == 0 ? oq : seg == 1 ? ok : ov;

  const int tid = threadIdx.x;
  const int w = tid >> 6, lane = tid & 63;
  const int quad = lane >> 4, l16 = lane & 15;
  const int wm = (w & 1) << 6, wn = (w >> 1) << 6;

#pragma unroll
  for (int nt = 0; nt < 4; ++nt) {
    int col = wn + nt * 16 + l16;
    int n = bn_l * 128 + col;            // 0..767 within segment
    float bval = bias[n];
    int h = n >> 6, d = n & 63;
#pragma unroll
    for (int mt = 0; mt < 4; ++mt) {
      int rowb = wm + mt * 16 + quad * 4;
#pragma unroll
      for (int r = 0; r < 4; ++r) {
        int m = bm * 128 + rowb + r;
        int s = m >> 1, b = m & 1;
        float v = acc[mt][nt][r] + bval;
        if (seg < 2)
          outp[((b * NHEADS + h) * SEQLEN + s) * HEADD + d] = cvtbf(v);
        else
          outp[((b * NHEADS + h) * HEADD + d) * SEQLEN + s] = cvtbf(v);
      }
    }
  }
}

// ---------------- kernel 4: flash-style causal attention ----------------
// grid (32, 24): 64 q-rows per block, one (b,h) per blockIdx.y. 4 waves x 16 rows.
__global__ __launch_bounds__(256, 2) void attn_kernel(
    const short* __restrict__ Q, const short* __restrict__ K,
    const short* __restrict__ Vt, short* __restrict__ Y) {
  __shared__ short sK[128 * 64];   // [t][d], swizzled
  __shared__ short sV[64 * 128];   // [d][t], swizzled
  __shared__ short sP[64 * 136];   // [q][t], padded stride 136
  const int tid = threadIdx.x;
  const int w = tid >> 6, lane = tid & 63;
  const int quad = lane >> 4, l16 = lane & 15;
  const int bh = blockIdx.y;
  const int q0 = blockIdx.x << 6;
  const short* Qb = Q + (size_t)bh * (SEQLEN * HEADD);
  const short* Kb = K + (size_t)bh * (SEQLEN * HEADD);
  const short* Vb = Vt + (size_t)bh * (SEQLEN * HEADD);  // [64][2048]

  // Q fragments in registers (A-operand: m=l16 row, k=quad*8+j)
  short8 aq[2];
#pragma unroll
  for (int ks = 0; ks < 2; ++ks)
    aq[ks] = *(const short8*)(Qb + (q0 + w * 16 + l16) * 64 + ks * 32 + quad * 8);

  float m_i[4], l_i[4];
  f32x4 acc_o[4];
  const f32x4 z4 = {0.f, 0.f, 0.f, 0.f};
#pragma unroll
  for (int r = 0; r < 4; ++r) { m_i[r] = -1e30f; l_i[r] = 0.f; }
#pragma unroll
  for (int nt = 0; nt < 4; ++nt) acc_o[nt] = z4;

  int gK[4], gV[4], lbase[4];
#pragma unroll
  for (int j = 0; j < 4; ++j) {
    int slot = w * 256 + j * 64 + lane;
    int rK = slot >> 3, cK = (slot & 7) ^ (rK & 7);
    gK[j] = rK * 64 + cK * 8;
    int rV = slot >> 4, cV = (slot & 15) ^ (rV & 15);
    gV[j] = rV * 2048 + cV * 8;
    lbase[j] = (w * 256 + j * 64) * 8;
  }

  const int ntiles = (blockIdx.x >> 1) + 1;
  const int qrow = q0 + w * 16 + quad * 4;
  const float SC = 0.125f * 1.44269504089f;   // scale * log2(e)

  for (int it = 0; it < ntiles; ++it) {
    const int t0 = it << 7;
    __syncthreads();
#pragma unroll
    for (int j = 0; j < 4; ++j) {
      gload16(Kb + t0 * 64 + gK[j], sK + lbase[j]);
      gload16(Vb + t0 + gV[j], sV + lbase[j]);
    }
    __syncthreads();

    // S = Q K^T  (8 n-tiles of 16 t-cols)
    f32x4 sc[8];
#pragma unroll
    for (int nt = 0; nt < 8; ++nt) sc[nt] = z4;
#pragma unroll
    for (int ks = 0; ks < 2; ++ks)
#pragma unroll
      for (int nt = 0; nt < 8; ++nt) {
        int row = nt * 16 + l16;
        int cp = (ks * 4 + quad) ^ (l16 & 7);
        short8 bk = *(const short8*)(sK + row * 64 + cp * 8);
        sc[nt] = __builtin_amdgcn_mfma_f32_16x16x32_bf16(aq[ks], bk, sc[nt], 0, 0, 0);
      }

    // scale + causal mask (base-2 domain)
    bool need_mask = (t0 + 127) > (q0 + w * 16);
    if (need_mask) {
#pragma unroll
      for (int nt = 0; nt < 8; ++nt)
#pragma unroll
        for (int r = 0; r < 4; ++r) {
          int t = t0 + nt * 16 + l16;
          float v = sc[nt][r] * SC;
          sc[nt][r] = (t > qrow + r) ? -1e30f : v;
        }
    } else {
#pragma unroll
      for (int nt = 0; nt < 8; ++nt)
#pragma unroll
        for (int r = 0; r < 4; ++r) sc[nt][r] *= SC;
    }

    // row max (over 8 n-tiles, then 16 lanes within quad)
    float mt_[4] = {-1e30f, -1e30f, -1e30f, -1e30f};
#pragma unroll
    for (int nt = 0; nt < 8; ++nt)
#pragma unroll
      for (int r = 0; r < 4; ++r) mt_[r] = fmaxf(mt_[r], sc[nt][r]);
#pragma unroll
    for (int off = 1; off <= 8; off <<= 1)
#pragma unroll
      for (int r = 0; r < 4; ++r) mt_[r] = fmaxf(mt_[r], __shfl_xor(mt_[r], off));

    float alpha[4];
#pragma unroll
    for (int r = 0; r < 4; ++r) {
      float mn = fmaxf(m_i[r], mt_[r]);
      alpha[r] = exp2f(m_i[r] - mn);
      m_i[r] = mn;
    }
    float ls[4] = {0.f, 0.f, 0.f, 0.f};
#pragma unroll
    for (int nt = 0; nt < 8; ++nt)
#pragma unroll
      for (int r = 0; r < 4; ++r) {
        float p = exp2f(sc[nt][r] - m_i[r]);
        sc[nt][r] = p;
        ls[r] += p;
      }
#pragma unroll
    for (int off = 1; off <= 8; off <<= 1)
#pragma unroll
      for (int r = 0; r < 4; ++r) ls[r] += __shfl_xor(ls[r], off);
#pragma unroll
    for (int r = 0; r < 4; ++r) l_i[r] = l_i[r] * alpha[r] + ls[r];
#pragma unroll
    for (int nt = 0; nt < 4; ++nt)
#pragma unroll
      for (int r = 0; r < 4; ++r) acc_o[nt][r] *= alpha[r];

    // P (C-layout) -> LDS bf16 (A-layout source); per-wave private rows
#pragma unroll
    for (int nt = 0; nt < 8; ++nt)
#pragma unroll
      for (int r = 0; r < 4; ++r)
        sP[(w * 16 + quad * 4 + r) * 136 + nt * 16 + l16] = cvtbf(sc[nt][r]);

    // O += P V  (k = t, 4 k-steps; n = d, 4 n-tiles)
#pragma unroll
    for (int kst = 0; kst < 4; ++kst) {
      short8 ap = *(const short8*)(sP + (w * 16 + l16) * 136 + kst * 32 + quad * 8);
#pragma unroll
      for (int nt = 0; nt < 4; ++nt) {
        int row = nt * 16 + l16;
        int cp = (kst * 4 + quad) ^ l16;      // 16 chunks/row swizzle
        short8 bv = *(const short8*)(sV + row * 128 + cp * 8);
        acc_o[nt] = __builtin_amdgcn_mfma_f32_16x16x32_bf16(ap, bv, acc_o[nt], 0, 0, 0);
      }
    }
  }

  // epilogue: Y[(s*2+b)][h*64+d] bf16
  const int b = bh / NHEADS, h = bh % NHEADS;
#pragma unroll
  for (int nt = 0; nt < 4; ++nt) {
    int col = h * 64 + nt * 16 + l16;
#pragma unroll
    for (int r = 0; r < 4; ++r) {
      int srow = q0 + w * 16 + quad * 4 + r;
      float v = acc_o[nt][r] / l_i[r];
      Y[(srow * 2 + b) * DMODEL + col] = cvtbf(v);
    }
  }
}

// ---------------- kernel 5: output projection (f32 out + bias) ----------------
__global__ __launch_bounds__(256, 2) void oproj_gemm(
    const short* __restrict__ A, const short* __restrict__ Bt,
    const float* __restrict__ bo, float* __restrict__ out) {
  __shared__ short sA[128 * 64];
  __shared__ short sB[128 * 64];
  f32x4 acc[4][4];
  const f32x4 z4 = {0.f, 0.f, 0.f, 0.f};
#pragma unroll
  for (int mt = 0; mt < 4; ++mt)
#pragma unroll
    for (int nt = 0; nt < 4; ++nt) acc[mt][nt] = z4;

  const int bm = blockIdx.x, bn = blockIdx.y;
  gemm_core(A, Bt, sA, sB, bm, bn, acc);

  const int tid = threadIdx.x;
  const int w = tid >> 6, lane = tid & 63;
  const int quad = lane >> 4, l16 = lane & 15;
  const int wm = (w & 1) << 6, wn = (w >> 1) << 6;

#pragma unroll
  for (int nt = 0; nt < 4; ++nt) {
    int n = bn * 128 + wn + nt * 16 + l16;
    float bval = bo[n];
#pragma unroll
    for (int mt = 0; mt < 4; ++mt) {
      int rowb = wm + mt * 16 + quad * 4;
#pragma unroll
      for (int r = 0; r < 4; ++r) {
        int m = bm * 128 + rowb + r;
        out[(size_t)m * 768 + n] = acc[mt][nt][r] + bval;
      }
    }
  }
}

extern "C" void kernel_launch(void* const* d_in, const int* in_sizes, int n_in,
                              void* d_out, int out_size, void* d_ws, size_t ws_size,
                              hipStream_t stream) {
  const float* x  = (const float*)d_in[0];
  const float* Wq = (const float*)d_in[1];
  const float* bq = (const float*)d_in[2];
  const float* Wk = (const float*)d_in[3];
  const float* bk = (const float*)d_in[4];
  const float* Wv = (const float*)d_in[5];
  const float* bv = (const float*)d_in[6];
  const float* Wo = (const float*)d_in[7];
  const float* bo = (const float*)d_in[8];
  float* out = (float*)d_out;

  short* ws  = (short*)d_ws;
  short* xb  = ws;                    // 3145728 shorts: x bf16 [4096][768]
  short* wt  = ws + 3145728;          // 1769472: [2304][768] Wq^T,Wk^T,Wv^T
  short* wot = ws + 4915200;          //  589824: Wo^T [768][768]
  short* qw  = ws + 5505024;          // 3145728: Q [b][h][s][64]
  short* kw  = ws + 8650752;          // 3145728: K [b][h][s][64]
  short* vw  = ws + 11796480;         // 3145728: V^T [b][h][64][s]
  short* yw  = ws + 14942208;         // 3145728: attn out [4096][768]

  cvt_x_kernel<<<1536, 256, 0, stream>>>(x, xb);
  transpose_w_kernel<<<dim3(24, 24, 4), dim3(32, 8), 0, stream>>>(Wq, Wk, Wv, Wo, wt, wot);
  qkv_gemm<<<dim3(32, 18), 256, 0, stream>>>(xb, wt, bq, bk, bv, qw, kw, vw);
  attn_kernel<<<dim3(32, 24), 256, 0, stream>>>(qw, kw, vw, yw);
  oproj_gemm<<<dim3(32, 6), 256, 0, stream>>>(yw, wot, bo, out);
}

// Round 2
// 175.349 us; speedup vs baseline: 1.1281x; 1.1281x over previous
//
#include <hip/hip_runtime.h>

typedef __attribute__((ext_vector_type(8))) short short8;
typedef __attribute__((ext_vector_type(4))) float f32x4;

#define NHEADS 12
#define SEQLEN 2048
#define HEADD  64
#define DMODEL 768

// f32 -> bf16 round-to-nearest-even
__device__ __forceinline__ short cvtbf(float f) {
  unsigned u = __builtin_bit_cast(unsigned, f);
  u += 0x7fffu + ((u >> 16) & 1u);
  return (short)(u >> 16);
}

// async global->LDS, 16B per lane; lds base must be wave-uniform (HW adds lane*16)
__device__ __forceinline__ void gload16(const void* g, void* l) {
  __builtin_amdgcn_global_load_lds((const __attribute__((address_space(1))) void*)g,
                                   (__attribute__((address_space(3))) void*)l, 16, 0, 0);
}

// ---------------- kernel 1: cast x (4096x768 f32) -> bf16 ----------------
__global__ void cvt_x_kernel(const float* __restrict__ x, short* __restrict__ o) {
  int i = blockIdx.x * 256 + threadIdx.x;     // 1536 blocks * 256 * 8 = 3145728
  const float* p = x + (size_t)i * 8;
  short8 v;
#pragma unroll
  for (int j = 0; j < 8; ++j) v[j] = cvtbf(p[j]);
  *(short8*)(o + (size_t)i * 8) = v;
}

// ------------- kernel 2: transpose+cast weights to bf16 [n][k] -------------
__global__ void transpose_w_kernel(const float* __restrict__ w0, const float* __restrict__ w1,
                                   const float* __restrict__ w2, const float* __restrict__ w3,
                                   short* __restrict__ wt, short* __restrict__ wot) {
  __shared__ float t[32][33];
  const float* W = blockIdx.z == 0 ? w0 : blockIdx.z == 1 ? w1 : blockIdx.z == 2 ? w2 : w3;
  short* O = blockIdx.z < 3 ? wt + (size_t)blockIdx.z * (768 * 768) : wot;
  int tx = threadIdx.x, ty = threadIdx.y;      // (32,8)
  int n0 = blockIdx.x * 32, k0 = blockIdx.y * 32;
#pragma unroll
  for (int j = 0; j < 4; ++j)
    t[ty + j * 8][tx] = W[(k0 + ty + j * 8) * 768 + n0 + tx];
  __syncthreads();
#pragma unroll
  for (int j = 0; j < 4; ++j)
    O[(n0 + ty + j * 8) * 768 + k0 + tx] = cvtbf(t[tx][ty + j * 8]);
}

// ------------- shared GEMM core: C[64 x BN] = A[64xK] * Bt[BNxK]^T -------------
// A: [M][768] bf16 row-major. Bt: [N][768] bf16 (k contig). BK=64, K=768.
// LDS XOR swizzle c' = c ^ (r&7) at 16B-chunk granularity.
template <int BN>
__device__ __forceinline__ void gemm_core64(const short* __restrict__ A,
                                            const short* __restrict__ Bt,
                                            short* sA, short* sB,
                                            int bm, int bn, f32x4 acc[2][BN / 32]) {
  constexpr int NT = BN / 32;
  const int tid = threadIdx.x;
  const int w = tid >> 6, lane = tid & 63;
  const int quad = lane >> 4, l16 = lane & 15;
  const int wm = (w & 1) * 32, wn = (w >> 1) * (BN / 2);

  int gA[2], lA[2], gB[NT], lB[NT];
#pragma unroll
  for (int j = 0; j < 2; ++j) {
    int slot = j * 256 + w * 64 + lane;
    int r = slot >> 3, c = (slot & 7) ^ (r & 7);
    gA[j] = (bm * 64 + r) * 768 + c * 8;
    lA[j] = (j * 256 + w * 64) * 8;
  }
#pragma unroll
  for (int j = 0; j < NT; ++j) {
    int slot = j * 256 + w * 64 + lane;
    int r = slot >> 3, c = (slot & 7) ^ (r & 7);
    gB[j] = (bn * BN + r) * 768 + c * 8;
    lB[j] = (j * 256 + w * 64) * 8;
  }

  for (int kt = 0; kt < 12; ++kt) {
    __syncthreads();
#pragma unroll
    for (int j = 0; j < 2; ++j) gload16(A + gA[j] + kt * 64, sA + lA[j]);
#pragma unroll
    for (int j = 0; j < NT; ++j) gload16(Bt + gB[j] + kt * 64, sB + lB[j]);
    __syncthreads();
#pragma unroll
    for (int ks = 0; ks < 2; ++ks) {
      short8 a[2], b[NT];
      int cp = (ks * 4 + quad) ^ (l16 & 7);
#pragma unroll
      for (int mt = 0; mt < 2; ++mt)
        a[mt] = *(const short8*)(sA + (wm + mt * 16 + l16) * 64 + cp * 8);
#pragma unroll
      for (int nt = 0; nt < NT; ++nt)
        b[nt] = *(const short8*)(sB + (wn + nt * 16 + l16) * 64 + cp * 8);
#pragma unroll
      for (int mt = 0; mt < 2; ++mt)
#pragma unroll
        for (int nt = 0; nt < NT; ++nt)
          acc[mt][nt] = __builtin_amdgcn_mfma_f32_16x16x32_bf16(a[mt], b[nt], acc[mt][nt], 0, 0, 0);
    }
  }
}

// ---------------- kernel 3: fused QKV projection ----------------
// grid (64, 18): bn/6 selects segment (0=Q,1=K,2=V), writes bf16:
//  Q,K -> [b][h][s][64]; V -> [b][h][64][s] (transposed for PV B-operand)
__global__ __launch_bounds__(256, 4) void qkv_gemm(
    const short* __restrict__ A, const short* __restrict__ Bt,
    const float* __restrict__ bq, const float* __restrict__ bk, const float* __restrict__ bv,
    short* __restrict__ oq, short* __restrict__ ok, short* __restrict__ ov) {
  __shared__ short sA[64 * 64];
  __shared__ short sB[128 * 64];
  f32x4 acc[2][4];
  const f32x4 z4 = {0.f, 0.f, 0.f, 0.f};
#pragma unroll
  for (int mt = 0; mt < 2; ++mt)
#pragma unroll
    for (int nt = 0; nt < 4; ++nt) acc[mt][nt] = z4;

  const int bm = blockIdx.x, bn = blockIdx.y;
  gemm_core64<128>(A, Bt, sA, sB, bm, bn, acc);

  const int seg = bn / 6, bn_l = bn % 6;
  const float* bias = seg == 0 ? bq : seg == 1 ? bk : bv;
  short* outp = seg == 0 ? oq : seg == 1 ? ok : ov;

  const int tid = threadIdx.x;
  const int w = tid >> 6, lane = tid & 63;
  const int quad = lane >> 4, l16 = lane & 15;
  const int wm = (w & 1) * 32, wn = (w >> 1) * 64;

#pragma unroll
  for (int nt = 0; nt < 4; ++nt) {
    int n = bn_l * 128 + wn + nt * 16 + l16;   // 0..767 within segment
    float bval = bias[n];
    int h = n >> 6, d = n & 63;
#pragma unroll
    for (int mt = 0; mt < 2; ++mt) {
      int rowb = wm + mt * 16 + quad * 4;
#pragma unroll
      for (int r = 0; r < 4; ++r) {
        int m = bm * 64 + rowb + r;
        int s = m >> 1, b = m & 1;
        float v = acc[mt][nt][r] + bval;
        if (seg < 2)
          outp[((b * NHEADS + h) * SEQLEN + s) * HEADD + d] = cvtbf(v);
        else
          outp[((b * NHEADS + h) * HEADD + d) * SEQLEN + s] = cvtbf(v);
      }
    }
  }
}

// ---------------- kernel 4: flash-style causal attention (Tk=64) ----------------
// 1D grid 768: heavy blocks first (qi = 31 - bid/24). 64 q-rows/block, 4 waves x 16 rows.
// LDS 24 KB -> 6 blocks/CU.
__global__ __launch_bounds__(256, 4) void attn_kernel(
    const short* __restrict__ Q, const short* __restrict__ K,
    const short* __restrict__ Vt, short* __restrict__ Y) {
  __shared__ short sK[64 * 64];   // [t][d], swizzled
  __shared__ short sV[64 * 64];   // [d][t], swizzled
  __shared__ short sP[64 * 64];   // [q][t], swizzled, wave-private rows
  const int tid = threadIdx.x;
  const int w = tid >> 6, lane = tid & 63;
  const int quad = lane >> 4, l16 = lane & 15;
  const int bid = blockIdx.x;
  const int qi = 31 - (bid / 24);           // heaviest (most KV tiles) first
  const int bh = bid % 24;
  const int q0 = qi << 6;
  const short* Qb = Q + (size_t)bh * (SEQLEN * HEADD);
  const short* Kb = K + (size_t)bh * (SEQLEN * HEADD);
  const short* Vb = Vt + (size_t)bh * (SEQLEN * HEADD);  // [64][2048]

  // Q fragments in registers (A-operand: m=l16 row, k=quad*8+j)
  short8 aq[2];
#pragma unroll
  for (int ks = 0; ks < 2; ++ks)
    aq[ks] = *(const short8*)(Qb + (q0 + w * 16 + l16) * 64 + ks * 32 + quad * 8);

  float m_i[4], l_i[4];
  f32x4 acc_o[4];
  const f32x4 z4 = {0.f, 0.f, 0.f, 0.f};
#pragma unroll
  for (int r = 0; r < 4; ++r) { m_i[r] = -1e30f; l_i[r] = 0.f; }
#pragma unroll
  for (int nt = 0; nt < 4; ++nt) acc_o[nt] = z4;

  int gK[2], gV[2], lbase[2];
#pragma unroll
  for (int j = 0; j < 2; ++j) {
    int slot = j * 256 + w * 64 + lane;       // 512 16B chunks per 64x64 tile
    int r = slot >> 3, c = (slot & 7) ^ (r & 7);
    gK[j] = r * 64 + c * 8;
    gV[j] = r * 2048 + c * 8;
    lbase[j] = (j * 256 + w * 64) * 8;
  }

  const int ntiles = qi + 1;
  const int qrow = q0 + w * 16 + quad * 4;
  const float SC = 0.125f * 1.44269504089f;   // scale * log2(e)

  for (int it = 0; it < ntiles; ++it) {
    const int t0 = it << 6;
    __syncthreads();
#pragma unroll
    for (int j = 0; j < 2; ++j) {
      gload16(Kb + t0 * 64 + gK[j], sK + lbase[j]);
      gload16(Vb + t0 + gV[j], sV + lbase[j]);
    }
    __syncthreads();

    // S = Q K^T  (4 n-tiles of 16 t-cols)
    f32x4 sc[4];
#pragma unroll
    for (int nt = 0; nt < 4; ++nt) sc[nt] = z4;
#pragma unroll
    for (int ks = 0; ks < 2; ++ks) {
      int cp = (ks * 4 + quad) ^ (l16 & 7);
#pragma unroll
      for (int nt = 0; nt < 4; ++nt) {
        short8 bk = *(const short8*)(sK + (nt * 16 + l16) * 64 + cp * 8);
        sc[nt] = __builtin_amdgcn_mfma_f32_16x16x32_bf16(aq[ks], bk, sc[nt], 0, 0, 0);
      }
    }

    // scale + causal mask (only the diagonal tile needs masking)
    if (it == ntiles - 1) {
#pragma unroll
      for (int nt = 0; nt < 4; ++nt)
#pragma unroll
        for (int r = 0; r < 4; ++r) {
          int t = t0 + nt * 16 + l16;
          float v = sc[nt][r] * SC;
          sc[nt][r] = (t > qrow + r) ? -1e30f : v;
        }
    } else {
#pragma unroll
      for (int nt = 0; nt < 4; ++nt)
#pragma unroll
        for (int r = 0; r < 4; ++r) sc[nt][r] *= SC;
    }

    // row max (over 4 n-tiles, then 16 lanes within quad)
    float mt_[4] = {-1e30f, -1e30f, -1e30f, -1e30f};
#pragma unroll
    for (int nt = 0; nt < 4; ++nt)
#pragma unroll
      for (int r = 0; r < 4; ++r) mt_[r] = fmaxf(mt_[r], sc[nt][r]);
#pragma unroll
    for (int off = 1; off <= 8; off <<= 1)
#pragma unroll
      for (int r = 0; r < 4; ++r) mt_[r] = fmaxf(mt_[r], __shfl_xor(mt_[r], off));

    float alpha[4];
#pragma unroll
    for (int r = 0; r < 4; ++r) {
      float mn = fmaxf(m_i[r], mt_[r]);
      alpha[r] = __builtin_amdgcn_exp2f(m_i[r] - mn);
      m_i[r] = mn;
    }
    float ls[4] = {0.f, 0.f, 0.f, 0.f};
#pragma unroll
    for (int nt = 0; nt < 4; ++nt)
#pragma unroll
      for (int r = 0; r < 4; ++r) {
        float p = __builtin_amdgcn_exp2f(sc[nt][r] - m_i[r]);
        sc[nt][r] = p;
        ls[r] += p;
      }
#pragma unroll
    for (int off = 1; off <= 8; off <<= 1)
#pragma unroll
      for (int r = 0; r < 4; ++r) ls[r] += __shfl_xor(ls[r], off);
#pragma unroll
    for (int r = 0; r < 4; ++r) l_i[r] = l_i[r] * alpha[r] + ls[r];
#pragma unroll
    for (int nt = 0; nt < 4; ++nt)
#pragma unroll
      for (int r = 0; r < 4; ++r) acc_o[nt][r] *= alpha[r];

    // P (C-layout) -> LDS bf16 (A-layout source); wave-private rows, XOR-swizzled
#pragma unroll
    for (int nt = 0; nt < 4; ++nt)
#pragma unroll
      for (int r = 0; r < 4; ++r) {
        int rq = w * 16 + quad * 4 + r;
        int t = nt * 16 + l16;
        int c = t >> 3;
        sP[rq * 64 + ((c ^ (rq & 7)) * 8 + (t & 7))] = cvtbf(sc[nt][r]);
      }

    // O += P V  (k = t, 2 k-steps; n = d, 4 n-tiles)
#pragma unroll
    for (int kst = 0; kst < 2; ++kst) {
      int rq = w * 16 + l16;
      int cpa = (kst * 4 + quad) ^ (rq & 7);
      short8 ap = *(const short8*)(sP + rq * 64 + cpa * 8);
#pragma unroll
      for (int nt = 0; nt < 4; ++nt) {
        int row = nt * 16 + l16;
        int cv = (kst * 4 + quad) ^ (row & 7);
        short8 bv = *(const short8*)(sV + row * 64 + cv * 8);
        acc_o[nt] = __builtin_amdgcn_mfma_f32_16x16x32_bf16(ap, bv, acc_o[nt], 0, 0, 0);
      }
    }
  }

  // epilogue: Y[(s*2+b)][h*64+d] bf16
  const int b = bh / NHEADS, h = bh % NHEADS;
#pragma unroll
  for (int r = 0; r < 4; ++r) {
    float rl = __builtin_amdgcn_rcpf(l_i[r]);
    int srow = q0 + w * 16 + quad * 4 + r;
#pragma unroll
    for (int nt = 0; nt < 4; ++nt) {
      int col = h * 64 + nt * 16 + l16;
      Y[(srow * 2 + b) * DMODEL + col] = cvtbf(acc_o[nt][r] * rl);
    }
  }
}

// ---------------- kernel 5: output projection (f32 out + bias) ----------------
// grid (64, 12): 64x64 tiles -> 768 blocks (3/CU)
__global__ __launch_bounds__(256, 4) void oproj_gemm(
    const short* __restrict__ A, const short* __restrict__ Bt,
    const float* __restrict__ bo, float* __restrict__ out) {
  __shared__ short sA[64 * 64];
  __shared__ short sB[64 * 64];
  f32x4 acc[2][2];
  const f32x4 z4 = {0.f, 0.f, 0.f, 0.f};
#pragma unroll
  for (int mt = 0; mt < 2; ++mt)
#pragma unroll
    for (int nt = 0; nt < 2; ++nt) acc[mt][nt] = z4;

  const int bm = blockIdx.x, bn = blockIdx.y;
  gemm_core64<64>(A, Bt, sA, sB, bm, bn, acc);

  const int tid = threadIdx.x;
  const int w = tid >> 6, lane = tid & 63;
  const int quad = lane >> 4, l16 = lane & 15;
  const int wm = (w & 1) * 32, wn = (w >> 1) * 32;

#pragma unroll
  for (int nt = 0; nt < 2; ++nt) {
    int n = bn * 64 + wn + nt * 16 + l16;
    float bval = bo[n];
#pragma unroll
    for (int mt = 0; mt < 2; ++mt) {
      int rowb = wm + mt * 16 + quad * 4;
#pragma unroll
      for (int r = 0; r < 4; ++r) {
        int m = bm * 64 + rowb + r;
        out[(size_t)m * 768 + n] = acc[mt][nt][r] + bval;
      }
    }
  }
}

extern "C" void kernel_launch(void* const* d_in, const int* in_sizes, int n_in,
                              void* d_out, int out_size, void* d_ws, size_t ws_size,
                              hipStream_t stream) {
  const float* x  = (const float*)d_in[0];
  const float* Wq = (const float*)d_in[1];
  const float* bq = (const float*)d_in[2];
  const float* Wk = (const float*)d_in[3];
  const float* bk = (const float*)d_in[4];
  const float* Wv = (const float*)d_in[5];
  const float* bv = (const float*)d_in[6];
  const float* Wo = (const float*)d_in[7];
  const float* bo = (const float*)d_in[8];
  float* out = (float*)d_out;

  short* ws  = (short*)d_ws;
  short* xb  = ws;                    // 3145728 shorts: x bf16 [4096][768]
  short* wt  = ws + 3145728;          // 1769472: [2304][768] Wq^T,Wk^T,Wv^T
  short* wot = ws + 4915200;          //  589824: Wo^T [768][768]
  short* qw  = ws + 5505024;          // 3145728: Q [b][h][s][64]
  short* kw  = ws + 8650752;          // 3145728: K [b][h][s][64]
  short* vw  = ws + 11796480;         // 3145728: V^T [b][h][64][s]
  short* yw  = ws + 14942208;         // 3145728: attn out [4096][768]

  cvt_x_kernel<<<1536, 256, 0, stream>>>(x, xb);
  transpose_w_kernel<<<dim3(24, 24, 4), dim3(32, 8), 0, stream>>>(Wq, Wk, Wv, Wo, wt, wot);
  qkv_gemm<<<dim3(64, 18), 256, 0, stream>>>(xb, wt, bq, bk, bv, qw, kw, vw);
  attn_kernel<<<768, 256, 0, stream>>>(qw, kw, vw, yw);
  oproj_gemm<<<dim3(64, 12), 256, 0, stream>>>(yw, wot, bo, out);
}

// Round 3
// 169.975 us; speedup vs baseline: 1.1637x; 1.0316x over previous
//
#include <hip/hip_runtime.h>

typedef __attribute__((ext_vector_type(8))) short short8;
typedef __attribute__((ext_vector_type(4))) float f32x4;

#define NHEADS 12
#define SEQLEN 2048
#define HEADD  64
#define DMODEL 768

// f32 -> bf16 round-to-nearest-even
__device__ __forceinline__ short cvtbf(float f) {
  unsigned u = __builtin_bit_cast(unsigned, f);
  u += 0x7fffu + ((u >> 16) & 1u);
  return (short)(u >> 16);
}

// async global->LDS, 16B per lane; lds base must be wave-uniform (HW adds lane*16)
__device__ __forceinline__ void gload16(const void* g, void* l) {
  __builtin_amdgcn_global_load_lds((const __attribute__((address_space(1))) void*)g,
                                   (__attribute__((address_space(3))) void*)l, 16, 0, 0);
}

// ---------------- kernel 1: cast x (4096x768 f32) -> bf16 ----------------
__global__ void cvt_x_kernel(const float* __restrict__ x, short* __restrict__ o) {
  int i = blockIdx.x * 256 + threadIdx.x;     // 1536 blocks * 256 * 8 = 3145728
  const float* p = x + (size_t)i * 8;
  short8 v;
#pragma unroll
  for (int j = 0; j < 8; ++j) v[j] = cvtbf(p[j]);
  *(short8*)(o + (size_t)i * 8) = v;
}

// ------------- kernel 2: transpose+cast weights to bf16 [n][k] -------------
__global__ void transpose_w_kernel(const float* __restrict__ w0, const float* __restrict__ w1,
                                   const float* __restrict__ w2, const float* __restrict__ w3,
                                   short* __restrict__ wt, short* __restrict__ wot) {
  __shared__ float t[32][33];
  const float* W = blockIdx.z == 0 ? w0 : blockIdx.z == 1 ? w1 : blockIdx.z == 2 ? w2 : w3;
  short* O = blockIdx.z < 3 ? wt + (size_t)blockIdx.z * (768 * 768) : wot;
  int tx = threadIdx.x, ty = threadIdx.y;      // (32,8)
  int n0 = blockIdx.x * 32, k0 = blockIdx.y * 32;
#pragma unroll
  for (int j = 0; j < 4; ++j)
    t[ty + j * 8][tx] = W[(k0 + ty + j * 8) * 768 + n0 + tx];
  __syncthreads();
#pragma unroll
  for (int j = 0; j < 4; ++j)
    O[(n0 + ty + j * 8) * 768 + k0 + tx] = cvtbf(t[tx][ty + j * 8]);
}

// ------------- shared GEMM core: C[64 x BN] = A[64xK] * Bt[BNxK]^T -------------
template <int BN>
__device__ __forceinline__ void gemm_core64(const short* __restrict__ A,
                                            const short* __restrict__ Bt,
                                            short* sA, short* sB,
                                            int bm, int bn, f32x4 acc[2][BN / 32]) {
  constexpr int NT = BN / 32;
  const int tid = threadIdx.x;
  const int w = tid >> 6, lane = tid & 63;
  const int quad = lane >> 4, l16 = lane & 15;
  const int wm = (w & 1) * 32, wn = (w >> 1) * (BN / 2);

  int gA[2], lA[2], gB[NT], lB[NT];
#pragma unroll
  for (int j = 0; j < 2; ++j) {
    int slot = j * 256 + w * 64 + lane;
    int r = slot >> 3, c = (slot & 7) ^ (r & 7);
    gA[j] = (bm * 64 + r) * 768 + c * 8;
    lA[j] = (j * 256 + w * 64) * 8;
  }
#pragma unroll
  for (int j = 0; j < NT; ++j) {
    int slot = j * 256 + w * 64 + lane;
    int r = slot >> 3, c = (slot & 7) ^ (r & 7);
    gB[j] = (bn * BN + r) * 768 + c * 8;
    lB[j] = (j * 256 + w * 64) * 8;
  }

  for (int kt = 0; kt < 12; ++kt) {
    __syncthreads();
#pragma unroll
    for (int j = 0; j < 2; ++j) gload16(A + gA[j] + kt * 64, sA + lA[j]);
#pragma unroll
    for (int j = 0; j < NT; ++j) gload16(Bt + gB[j] + kt * 64, sB + lB[j]);
    __syncthreads();
#pragma unroll
    for (int ks = 0; ks < 2; ++ks) {
      short8 a[2], b[NT];
      int cp = (ks * 4 + quad) ^ (l16 & 7);
#pragma unroll
      for (int mt = 0; mt < 2; ++mt)
        a[mt] = *(const short8*)(sA + (wm + mt * 16 + l16) * 64 + cp * 8);
#pragma unroll
      for (int nt = 0; nt < NT; ++nt)
        b[nt] = *(const short8*)(sB + (wn + nt * 16 + l16) * 64 + cp * 8);
#pragma unroll
      for (int mt = 0; mt < 2; ++mt)
#pragma unroll
        for (int nt = 0; nt < NT; ++nt)
          acc[mt][nt] = __builtin_amdgcn_mfma_f32_16x16x32_bf16(a[mt], b[nt], acc[mt][nt], 0, 0, 0);
    }
  }
}

// ---------------- kernel 3: fused QKV projection ----------------
__global__ __launch_bounds__(256, 4) void qkv_gemm(
    const short* __restrict__ A, const short* __restrict__ Bt,
    const float* __restrict__ bq, const float* __restrict__ bk, const float* __restrict__ bv,
    short* __restrict__ oq, short* __restrict__ ok, short* __restrict__ ov) {
  __shared__ short sA[64 * 64];
  __shared__ short sB[128 * 64];
  f32x4 acc[2][4];
  const f32x4 z4 = {0.f, 0.f, 0.f, 0.f};
#pragma unroll
  for (int mt = 0; mt < 2; ++mt)
#pragma unroll
    for (int nt = 0; nt < 4; ++nt) acc[mt][nt] = z4;

  const int bm = blockIdx.x, bn = blockIdx.y;
  gemm_core64<128>(A, Bt, sA, sB, bm, bn, acc);

  const int seg = bn / 6, bn_l = bn % 6;
  const float* bias = seg == 0 ? bq : seg == 1 ? bk : bv;
  short* outp = seg == 0 ? oq : seg == 1 ? ok : ov;

  const int tid = threadIdx.x;
  const int w = tid >> 6, lane = tid & 63;
  const int quad = lane >> 4, l16 = lane & 15;
  const int wm = (w & 1) * 32, wn = (w >> 1) * 64;

#pragma unroll
  for (int nt = 0; nt < 4; ++nt) {
    int n = bn_l * 128 + wn + nt * 16 + l16;   // 0..767 within segment
    float bval = bias[n];
    int h = n >> 6, d = n & 63;
#pragma unroll
    for (int mt = 0; mt < 2; ++mt) {
      int rowb = wm + mt * 16 + quad * 4;
#pragma unroll
      for (int r = 0; r < 4; ++r) {
        int m = bm * 64 + rowb + r;
        int s = m >> 1, b = m & 1;
        float v = acc[mt][nt][r] + bval;
        if (seg < 2)
          outp[((b * NHEADS + h) * SEQLEN + s) * HEADD + d] = cvtbf(v);
        else
          outp[((b * NHEADS + h) * HEADD + d) * SEQLEN + s] = cvtbf(v);
      }
    }
  }
}

// -------- attn work table: 48 entries {qi | tstart<<8 | ntiles<<16}, heavy-first --------
#define AE(qi, ts, nt) ((qi) | ((ts) << 8) | ((nt) << 16))
__device__ const int ATTN_TAB[48] = {
  // 16-tile blocks
  AE(15,0,16), AE(16,0,16), AE(17,0,16), AE(18,0,16), AE(19,0,16), AE(20,0,16),
  AE(21,0,16), AE(22,0,16), AE(23,0,16), AE(24,0,16), AE(25,0,16), AE(26,0,16),
  AE(27,0,16), AE(28,0,16), AE(29,0,16), AE(30,0,16), AE(31,0,16), AE(31,16,16),
  AE(14,0,15), AE(30,16,15),
  AE(13,0,14), AE(29,16,14),
  AE(12,0,13), AE(28,16,13),
  AE(11,0,12), AE(27,16,12),
  AE(10,0,11), AE(26,16,11),
  AE( 9,0,10), AE(25,16,10),
  AE( 8,0, 9), AE(24,16, 9),
  AE( 7,0, 8), AE(23,16, 8),
  AE( 6,0, 7), AE(22,16, 7),
  AE( 5,0, 6), AE(21,16, 6),
  AE( 4,0, 5), AE(20,16, 5),
  AE( 3,0, 4), AE(19,16, 4),
  AE( 2,0, 3), AE(18,16, 3),
  AE( 1,0, 2), AE(17,16, 2),
  AE( 0,0, 1), AE(16,16, 1),
};

// ---------------- kernel 4: split-K flash attention, m==0 softmax ----------------
// grid 1152 = 48 entries x 24 bh. qi<16: single chunk, writes Y directly.
// qi>=16: 2 chunks write unnormalized (O,l) f32 partials; merge kernel combines.
__global__ __launch_bounds__(256, 6) void attn_kernel(
    const short* __restrict__ Q, const short* __restrict__ K,
    const short* __restrict__ Vt, short* __restrict__ Y,
    float* __restrict__ Of, float* __restrict__ lf) {
  __shared__ short sK[64 * 64];   // [t][d], swizzled
  __shared__ short sV[64 * 64];   // [d][t], swizzled
  __shared__ short sP[64 * 64];   // [q][t], swizzled, wave-private rows
  const int tid = threadIdx.x;
  const int w = tid >> 6, lane = tid & 63;
  const int quad = lane >> 4, l16 = lane & 15;
  const int e = ATTN_TAB[blockIdx.x / 24];
  const int bh = blockIdx.x % 24;
  const int qi = e & 255, ts = (e >> 8) & 255, ntl = e >> 16;
  const int q0 = qi << 6;
  const short* Qb = Q + (size_t)bh * (SEQLEN * HEADD);
  const short* Kb = K + (size_t)bh * (SEQLEN * HEADD);
  const short* Vb = Vt + (size_t)bh * (SEQLEN * HEADD);  // [64][2048]

  // Q fragments in registers (A-operand: m=l16 row, k=quad*8+j)
  short8 aq[2];
#pragma unroll
  for (int ks = 0; ks < 2; ++ks)
    aq[ks] = *(const short8*)(Qb + (q0 + w * 16 + l16) * 64 + ks * 32 + quad * 8);

  float l_lane[4] = {0.f, 0.f, 0.f, 0.f};
  f32x4 acc_o[4];
  const f32x4 z4 = {0.f, 0.f, 0.f, 0.f};
#pragma unroll
  for (int nt = 0; nt < 4; ++nt) acc_o[nt] = z4;

  int gK[2], gV[2], lbase[2];
#pragma unroll
  for (int j = 0; j < 2; ++j) {
    int slot = j * 256 + w * 64 + lane;       // 512 16B chunks per 64x64 tile
    int r = slot >> 3, c = (slot & 7) ^ (r & 7);
    gK[j] = r * 64 + c * 8;
    gV[j] = r * 2048 + c * 8;
    lbase[j] = (j * 256 + w * 64) * 8;
  }

  const int qrow = q0 + w * 16 + quad * 4;
  const float SC = 0.125f * 1.44269504089f;   // scale * log2(e)

  for (int it = ts; it < ts + ntl; ++it) {
    const int t0 = it << 6;
    __syncthreads();
#pragma unroll
    for (int j = 0; j < 2; ++j) {
      gload16(Kb + t0 * 64 + gK[j], sK + lbase[j]);
      gload16(Vb + t0 + gV[j], sV + lbase[j]);
    }
    __syncthreads();

    // S = Q K^T  (4 n-tiles of 16 t-cols)
    f32x4 sc[4];
#pragma unroll
    for (int nt = 0; nt < 4; ++nt) sc[nt] = z4;
#pragma unroll
    for (int ks = 0; ks < 2; ++ks) {
      int cp = (ks * 4 + quad) ^ (l16 & 7);
#pragma unroll
      for (int nt = 0; nt < 4; ++nt) {
        short8 bk = *(const short8*)(sK + (nt * 16 + l16) * 64 + cp * 8);
        sc[nt] = __builtin_amdgcn_mfma_f32_16x16x32_bf16(aq[ks], bk, sc[nt], 0, 0, 0);
      }
    }

    // causal mask on the diagonal tile (raw scores; exp2 of masked -> 0)
    if (it == qi) {
#pragma unroll
      for (int nt = 0; nt < 4; ++nt)
#pragma unroll
        for (int r = 0; r < 4; ++r) {
          int t = t0 + nt * 16 + l16;
          if (t > qrow + r) sc[nt][r] = -1e30f;
        }
    }

    // p = exp2(s*SC); accumulate l per-lane; write P to LDS (wave-private rows)
#pragma unroll
    for (int nt = 0; nt < 4; ++nt)
#pragma unroll
      for (int r = 0; r < 4; ++r) {
        float p = __builtin_amdgcn_exp2f(sc[nt][r] * SC);
        l_lane[r] += p;
        int rq = w * 16 + quad * 4 + r;
        int t = nt * 16 + l16;
        int c = t >> 3;
        sP[rq * 64 + ((c ^ (rq & 7)) * 8 + (t & 7))] = cvtbf(p);
      }

    // O += P V  (k = t, 2 k-steps; n = d, 4 n-tiles)
#pragma unroll
    for (int kst = 0; kst < 2; ++kst) {
      int rq = w * 16 + l16;
      int cpa = (kst * 4 + quad) ^ (rq & 7);
      short8 ap = *(const short8*)(sP + rq * 64 + cpa * 8);
#pragma unroll
      for (int nt = 0; nt < 4; ++nt) {
        int row = nt * 16 + l16;
        int cv = (kst * 4 + quad) ^ (row & 7);
        short8 bv = *(const short8*)(sV + row * 64 + cv * 8);
        acc_o[nt] = __builtin_amdgcn_mfma_f32_16x16x32_bf16(ap, bv, acc_o[nt], 0, 0, 0);
      }
    }
  }

  // reduce l across the 16 t-lanes (stays within quad group)
#pragma unroll
  for (int off = 1; off <= 8; off <<= 1)
#pragma unroll
    for (int r = 0; r < 4; ++r) l_lane[r] += __shfl_xor(l_lane[r], off);

  if (qi < 16) {
    // single chunk: normalize + write Y[(s*2+b)][h*64+d] bf16
    const int b = bh / NHEADS, h = bh % NHEADS;
#pragma unroll
    for (int r = 0; r < 4; ++r) {
      float rl = __builtin_amdgcn_rcpf(l_lane[r]);
      int srow = q0 + w * 16 + quad * 4 + r;
#pragma unroll
      for (int nt = 0; nt < 4; ++nt)
        Y[(srow * 2 + b) * DMODEL + h * 64 + nt * 16 + l16] = cvtbf(acc_o[nt][r] * rl);
    }
  } else {
    // write unnormalized partial (O, l) f32
    const int c = (ts == 0) ? 0 : 1;
    const int slot = (bh * 16 + (qi - 16)) * 2 + c;
    float* Ob = Of + (size_t)slot * 4096;
#pragma unroll
    for (int r = 0; r < 4; ++r) {
      int row = w * 16 + quad * 4 + r;
#pragma unroll
      for (int nt = 0; nt < 4; ++nt)
        Ob[row * 64 + nt * 16 + l16] = acc_o[nt][r];
      if (l16 == 0) lf[slot * 64 + row] = l_lane[r];
    }
  }
}

// ---------------- kernel 4b: merge 2 partials for qi>=16 ----------------
// grid 384 = 16 qi x 24 bh; 256 threads, 16 elems each
__global__ void attn_merge(const float* __restrict__ Of, const float* __restrict__ lf,
                           short* __restrict__ Y) {
  const int bh = blockIdx.x % 24, qi = 16 + blockIdx.x / 24;
  const int slot = (bh * 16 + (qi - 16)) * 2;
  const float* O0 = Of + (size_t)slot * 4096;
  const float* O1 = O0 + 4096;
  const float* L0 = lf + slot * 64;
  const int b = bh / NHEADS, h = bh % NHEADS;
  const int tid = threadIdx.x;
#pragma unroll
  for (int j = 0; j < 16; ++j) {
    int idx = j * 256 + tid;
    int row = idx >> 6, col = idx & 63;
    float l = L0[row] + L0[64 + row];
    float v = (O0[idx] + O1[idx]) * __builtin_amdgcn_rcpf(l);
    int srow = qi * 64 + row;
    Y[(srow * 2 + b) * DMODEL + h * 64 + col] = cvtbf(v);
  }
}

// ---------------- kernel 5: output projection (f32 out + bias) ----------------
__global__ __launch_bounds__(256, 4) void oproj_gemm(
    const short* __restrict__ A, const short* __restrict__ Bt,
    const float* __restrict__ bo, float* __restrict__ out) {
  __shared__ short sA[64 * 64];
  __shared__ short sB[64 * 64];
  f32x4 acc[2][2];
  const f32x4 z4 = {0.f, 0.f, 0.f, 0.f};
#pragma unroll
  for (int mt = 0; mt < 2; ++mt)
#pragma unroll
    for (int nt = 0; nt < 2; ++nt) acc[mt][nt] = z4;

  const int bm = blockIdx.x, bn = blockIdx.y;
  gemm_core64<64>(A, Bt, sA, sB, bm, bn, acc);

  const int tid = threadIdx.x;
  const int w = tid >> 6, lane = tid & 63;
  const int quad = lane >> 4, l16 = lane & 15;
  const int wm = (w & 1) * 32, wn = (w >> 1) * 32;

#pragma unroll
  for (int nt = 0; nt < 2; ++nt) {
    int n = bn * 64 + wn + nt * 16 + l16;
    float bval = bo[n];
#pragma unroll
    for (int mt = 0; mt < 2; ++mt) {
      int rowb = wm + mt * 16 + quad * 4;
#pragma unroll
      for (int r = 0; r < 4; ++r) {
        int m = bm * 64 + rowb + r;
        out[(size_t)m * 768 + n] = acc[mt][nt][r] + bval;
      }
    }
  }
}

extern "C" void kernel_launch(void* const* d_in, const int* in_sizes, int n_in,
                              void* d_out, int out_size, void* d_ws, size_t ws_size,
                              hipStream_t stream) {
  const float* x  = (const float*)d_in[0];
  const float* Wq = (const float*)d_in[1];
  const float* bq = (const float*)d_in[2];
  const float* Wk = (const float*)d_in[3];
  const float* bk = (const float*)d_in[4];
  const float* Wv = (const float*)d_in[5];
  const float* bv = (const float*)d_in[6];
  const float* Wo = (const float*)d_in[7];
  const float* bo = (const float*)d_in[8];
  float* out = (float*)d_out;

  short* ws  = (short*)d_ws;
  short* xb  = ws;                    // 3145728 shorts: x bf16 [4096][768]
  short* wt  = ws + 3145728;          // 1769472: [2304][768] Wq^T,Wk^T,Wv^T
  short* wot = ws + 4915200;          //  589824: Wo^T [768][768]
  short* qw  = ws + 5505024;          // 3145728: Q [b][h][s][64]
  short* kw  = ws + 8650752;          // 3145728: K [b][h][s][64]
  short* vw  = ws + 11796480;         // 3145728: V^T [b][h][64][s]
  short* yw  = ws + 14942208;         // 3145728: attn out [4096][768]
  float* Of  = (float*)(ws + 18087936); // 3145728 f32: 768 slots x 64x64 partial O
  float* lf  = Of + 3145728;            //   49152 f32: 768 slots x 64 partial l

  cvt_x_kernel<<<1536, 256, 0, stream>>>(x, xb);
  transpose_w_kernel<<<dim3(24, 24, 4), dim3(32, 8), 0, stream>>>(Wq, Wk, Wv, Wo, wt, wot);
  qkv_gemm<<<dim3(64, 18), 256, 0, stream>>>(xb, wt, bq, bk, bv, qw, kw, vw);
  attn_kernel<<<1152, 256, 0, stream>>>(qw, kw, vw, yw, Of, lf);
  attn_merge<<<384, 256, 0, stream>>>(Of, lf, yw);
  oproj_gemm<<<dim3(64, 12), 256, 0, stream>>>(yw, wot, bo, out);
}

// Round 4
// 167.693 us; speedup vs baseline: 1.1796x; 1.0136x over previous
//
#include <hip/hip_runtime.h>

typedef __attribute__((ext_vector_type(8))) short short8;
typedef __attribute__((ext_vector_type(4))) float f32x4;

#define NHEADS 12
#define SEQLEN 2048
#define HEADD  64
#define DMODEL 768

// f32 -> bf16 round-to-nearest-even
__device__ __forceinline__ short cvtbf(float f) {
  unsigned u = __builtin_bit_cast(unsigned, f);
  u += 0x7fffu + ((u >> 16) & 1u);
  return (short)(u >> 16);
}

// async global->LDS, 16B per lane; lds base must be wave-uniform (HW adds lane*16)
__device__ __forceinline__ void gload16(const void* g, void* l) {
  __builtin_amdgcn_global_load_lds((const __attribute__((address_space(1))) void*)g,
                                   (__attribute__((address_space(3))) void*)l, 16, 0, 0);
}

// store high 16 bits of f32 (bf16 truncation) to LDS in ONE instruction, no VALU
__device__ __forceinline__ void ds_write_hi16(short* p, float v) {
  asm volatile("ds_write_b16_d16_hi %0, %1"
               : : "v"((__attribute__((address_space(3))) short*)p), "v"(v) : "memory");
}

// ---------------- kernel 1: cast x (4096x768 f32) -> bf16 ----------------
__global__ void cvt_x_kernel(const float* __restrict__ x, short* __restrict__ o) {
  int i = blockIdx.x * 256 + threadIdx.x;     // 1536 blocks * 256 * 8 = 3145728
  const float* p = x + (size_t)i * 8;
  short8 v;
#pragma unroll
  for (int j = 0; j < 8; ++j) v[j] = cvtbf(p[j]);
  *(short8*)(o + (size_t)i * 8) = v;
}

// ------------- kernel 2: transpose+cast weights to bf16 [n][k] -------------
__global__ void transpose_w_kernel(const float* __restrict__ w0, const float* __restrict__ w1,
                                   const float* __restrict__ w2, const float* __restrict__ w3,
                                   short* __restrict__ wt, short* __restrict__ wot) {
  __shared__ float t[32][33];
  const float* W = blockIdx.z == 0 ? w0 : blockIdx.z == 1 ? w1 : blockIdx.z == 2 ? w2 : w3;
  short* O = blockIdx.z < 3 ? wt + (size_t)blockIdx.z * (768 * 768) : wot;
  int tx = threadIdx.x, ty = threadIdx.y;      // (32,8)
  int n0 = blockIdx.x * 32, k0 = blockIdx.y * 32;
#pragma unroll
  for (int j = 0; j < 4; ++j)
    t[ty + j * 8][tx] = W[(k0 + ty + j * 8) * 768 + n0 + tx];
  __syncthreads();
#pragma unroll
  for (int j = 0; j < 4; ++j)
    O[(n0 + ty + j * 8) * 768 + k0 + tx] = cvtbf(t[tx][ty + j * 8]);
}

// ------------- shared GEMM core: C[64 x BN] = A[64xK] * Bt[BNxK]^T -------------
template <int BN>
__device__ __forceinline__ void gemm_core64(const short* __restrict__ A,
                                            const short* __restrict__ Bt,
                                            short* sA, short* sB,
                                            int bm, int bn, f32x4 acc[2][BN / 32]) {
  constexpr int NT = BN / 32;
  const int tid = threadIdx.x;
  const int w = tid >> 6, lane = tid & 63;
  const int quad = lane >> 4, l16 = lane & 15;
  const int wm = (w & 1) * 32, wn = (w >> 1) * (BN / 2);

  int gA[2], lA[2], gB[NT], lB[NT];
#pragma unroll
  for (int j = 0; j < 2; ++j) {
    int slot = j * 256 + w * 64 + lane;
    int r = slot >> 3, c = (slot & 7) ^ (r & 7);
    gA[j] = (bm * 64 + r) * 768 + c * 8;
    lA[j] = (j * 256 + w * 64) * 8;
  }
#pragma unroll
  for (int j = 0; j < NT; ++j) {
    int slot = j * 256 + w * 64 + lane;
    int r = slot >> 3, c = (slot & 7) ^ (r & 7);
    gB[j] = (bn * BN + r) * 768 + c * 8;
    lB[j] = (j * 256 + w * 64) * 8;
  }

  for (int kt = 0; kt < 12; ++kt) {
    __syncthreads();
#pragma unroll
    for (int j = 0; j < 2; ++j) gload16(A + gA[j] + kt * 64, sA + lA[j]);
#pragma unroll
    for (int j = 0; j < NT; ++j) gload16(Bt + gB[j] + kt * 64, sB + lB[j]);
    __syncthreads();
#pragma unroll
    for (int ks = 0; ks < 2; ++ks) {
      short8 a[2], b[NT];
      int cp = (ks * 4 + quad) ^ (l16 & 7);
#pragma unroll
      for (int mt = 0; mt < 2; ++mt)
        a[mt] = *(const short8*)(sA + (wm + mt * 16 + l16) * 64 + cp * 8);
#pragma unroll
      for (int nt = 0; nt < NT; ++nt)
        b[nt] = *(const short8*)(sB + (wn + nt * 16 + l16) * 64 + cp * 8);
#pragma unroll
      for (int mt = 0; mt < 2; ++mt)
#pragma unroll
        for (int nt = 0; nt < NT; ++nt)
          acc[mt][nt] = __builtin_amdgcn_mfma_f32_16x16x32_bf16(a[mt], b[nt], acc[mt][nt], 0, 0, 0);
    }
  }
}

// ---------------- kernel 3: fused QKV projection ----------------
// Q is pre-scaled by 0.125*log2(e) so attention needs no per-score multiply.
__global__ __launch_bounds__(256, 4) void qkv_gemm(
    const short* __restrict__ A, const short* __restrict__ Bt,
    const float* __restrict__ bq, const float* __restrict__ bk, const float* __restrict__ bv,
    short* __restrict__ oq, short* __restrict__ ok, short* __restrict__ ov) {
  __shared__ short sA[64 * 64];
  __shared__ short sB[128 * 64];
  f32x4 acc[2][4];
  const f32x4 z4 = {0.f, 0.f, 0.f, 0.f};
#pragma unroll
  for (int mt = 0; mt < 2; ++mt)
#pragma unroll
    for (int nt = 0; nt < 4; ++nt) acc[mt][nt] = z4;

  const int bm = blockIdx.x, bn = blockIdx.y;
  gemm_core64<128>(A, Bt, sA, sB, bm, bn, acc);

  const int seg = bn / 6, bn_l = bn % 6;
  const float* bias = seg == 0 ? bq : seg == 1 ? bk : bv;
  short* outp = seg == 0 ? oq : seg == 1 ? ok : ov;

  const int tid = threadIdx.x;
  const int w = tid >> 6, lane = tid & 63;
  const int quad = lane >> 4, l16 = lane & 15;
  const int wm = (w & 1) * 32, wn = (w >> 1) * 64;

#pragma unroll
  for (int nt = 0; nt < 4; ++nt) {
    int n = bn_l * 128 + wn + nt * 16 + l16;   // 0..767 within segment
    float bval = bias[n];
    int h = n >> 6, d = n & 63;
#pragma unroll
    for (int mt = 0; mt < 2; ++mt) {
      int rowb = wm + mt * 16 + quad * 4;
#pragma unroll
      for (int r = 0; r < 4; ++r) {
        int m = bm * 64 + rowb + r;
        int s = m >> 1, b = m & 1;
        float v = acc[mt][nt][r] + bval;
        if (seg == 0) v *= 0.1803368801f;      // 0.125 * log2(e)
        if (seg < 2)
          outp[((b * NHEADS + h) * SEQLEN + s) * HEADD + d] = cvtbf(v);
        else
          outp[((b * NHEADS + h) * HEADD + d) * SEQLEN + s] = cvtbf(v);
      }
    }
  }
}

// -------- attn work table: 80 entries {qi | ts<<8 | ntl<<16}, heavy-first --------
#define AE(qi, ts, nt) ((qi) | ((ts) << 8) | ((nt) << 16))
__device__ const int ATTN_TAB[80] = {
  AE(31,0,8), AE(31,8,8), AE(31,16,8), AE(31,24,8),
  AE(30,0,8), AE(30,8,8), AE(30,16,8),
  AE(29,0,8), AE(29,8,8), AE(29,16,8),
  AE(28,0,8), AE(28,8,8), AE(28,16,8),
  AE(27,0,8), AE(27,8,8), AE(27,16,8),
  AE(26,0,8), AE(26,8,8), AE(26,16,8),
  AE(25,0,8), AE(25,8,8), AE(25,16,8),
  AE(24,0,8), AE(24,8,8), AE(24,16,8),
  AE(23,0,8), AE(23,8,8), AE(23,16,8),
  AE(22,0,8), AE(22,8,8),
  AE(21,0,8), AE(21,8,8),
  AE(20,0,8), AE(20,8,8),
  AE(19,0,8), AE(19,8,8),
  AE(18,0,8), AE(18,8,8),
  AE(17,0,8), AE(17,8,8),
  AE(16,0,8), AE(16,8,8),
  AE(15,0,8), AE(15,8,8),
  AE(14,0,8), AE(13,0,8), AE(12,0,8), AE(11,0,8),
  AE(10,0,8), AE(9,0,8),  AE(8,0,8),  AE(7,0,8),
  AE(30,24,7), AE(22,16,7), AE(14,8,7), AE(6,0,7),
  AE(29,24,6), AE(21,16,6), AE(13,8,6), AE(5,0,6),
  AE(28,24,5), AE(20,16,5), AE(12,8,5), AE(4,0,5),
  AE(27,24,4), AE(19,16,4), AE(11,8,4), AE(3,0,4),
  AE(26,24,3), AE(18,16,3), AE(10,8,3), AE(2,0,3),
  AE(25,24,2), AE(17,16,2), AE(9,8,2),  AE(1,0,2),
  AE(24,24,1), AE(16,16,1), AE(8,8,1),  AE(0,0,1),
};
// partial-slot base per qi (qi>=8 only; 72 slots per bh)
__device__ const int PBASE[32] = {
  0,0,0,0,0,0,0,0,
  0,2,4,6,8,10,12,14,
  16,19,22,25,28,31,34,37,
  40,44,48,52,56,60,64,68};

// ---------------- kernel 4: split-K flash attention ----------------
// grid 1920 = 80 entries x 24 bh. qi<8: single chunk -> Y direct.
// qi>=8: chunks write unnormalized (O,l) f32 partials; merge combines 2-4.
// Double-buffered K/V (one barrier per tile); l computed via ones-MFMA.
__global__ __launch_bounds__(256, 4) void attn_kernel(
    const short* __restrict__ Q, const short* __restrict__ K,
    const short* __restrict__ Vt, short* __restrict__ Y,
    float* __restrict__ Of, float* __restrict__ lf) {
  __shared__ short sK[2][64 * 64];   // [t][d], swizzled
  __shared__ short sV[2][64 * 64];   // [d][t], swizzled
  __shared__ short sP[64 * 64];      // [q][t], swizzled, wave-private rows
  const int tid = threadIdx.x;
  const int w = tid >> 6, lane = tid & 63;
  const int quad = lane >> 4, l16 = lane & 15;
  const int e = ATTN_TAB[blockIdx.x / 24];
  const int bh = blockIdx.x % 24;
  const int qi = e & 255, ts = (e >> 8) & 255, ntl = e >> 16;
  const int q0 = qi << 6;
  const short* Qb = Q + (size_t)bh * (SEQLEN * HEADD);
  const short* Kb = K + (size_t)bh * (SEQLEN * HEADD);
  const short* Vb = Vt + (size_t)bh * (SEQLEN * HEADD);  // [64][2048]

  // Q fragments in registers (A-operand: m=l16 row, k=quad*8+j); pre-scaled
  short8 aq[2];
#pragma unroll
  for (int ks = 0; ks < 2; ++ks)
    aq[ks] = *(const short8*)(Qb + (q0 + w * 16 + l16) * 64 + ks * 32 + quad * 8);

  const short8 bones = {0x3F80, 0x3F80, 0x3F80, 0x3F80, 0x3F80, 0x3F80, 0x3F80, 0x3F80};
  f32x4 acc_o[4], acc_l;
  const f32x4 z4 = {0.f, 0.f, 0.f, 0.f};
#pragma unroll
  for (int nt = 0; nt < 4; ++nt) acc_o[nt] = z4;
  acc_l = z4;

  int gK[2], gV[2], lbase[2];
#pragma unroll
  for (int j = 0; j < 2; ++j) {
    int slot = j * 256 + w * 64 + lane;       // 512 16B chunks per 64x64 tile
    int r = slot >> 3, c = (slot & 7) ^ (r & 7);
    gK[j] = r * 64 + c * 8;
    gV[j] = r * 2048 + c * 8;
    lbase[j] = (j * 256 + w * 64) * 8;
  }

  const int qrow = q0 + w * 16 + quad * 4;
  const int tend = ts + ntl;

  // prologue: issue first tile into buffer 0
#pragma unroll
  for (int j = 0; j < 2; ++j) {
    gload16(Kb + (ts << 6) * 64 + gK[j], &sK[0][lbase[j]]);
    gload16(Vb + (ts << 6) + gV[j], &sV[0][lbase[j]]);
  }

  int pb = 0;
  for (int it = ts; it < tend; ++it) {
    __syncthreads();    // drains this wave's loads into buf pb; all waves done reading buf pb^1
    if (it + 1 < tend) {
      const int t1 = (it + 1) << 6;
#pragma unroll
      for (int j = 0; j < 2; ++j) {
        gload16(Kb + t1 * 64 + gK[j], &sK[pb ^ 1][lbase[j]]);
        gload16(Vb + t1 + gV[j], &sV[pb ^ 1][lbase[j]]);
      }
    }
    const short* sk = sK[pb];
    const short* sv = sV[pb];

    // S = Q K^T  (4 n-tiles of 16 t-cols)
    f32x4 sc[4];
#pragma unroll
    for (int nt = 0; nt < 4; ++nt) sc[nt] = z4;
#pragma unroll
    for (int ks = 0; ks < 2; ++ks) {
      int cp = (ks * 4 + quad) ^ (l16 & 7);
#pragma unroll
      for (int nt = 0; nt < 4; ++nt) {
        short8 bk = *(const short8*)(sk + (nt * 16 + l16) * 64 + cp * 8);
        sc[nt] = __builtin_amdgcn_mfma_f32_16x16x32_bf16(aq[ks], bk, sc[nt], 0, 0, 0);
      }
    }

    // causal mask on the diagonal tile
    if (it == qi) {
      const int t0 = it << 6;
#pragma unroll
      for (int nt = 0; nt < 4; ++nt)
#pragma unroll
        for (int r = 0; r < 4; ++r) {
          int t = t0 + nt * 16 + l16;
          if (t > qrow + r) sc[nt][r] = -1e30f;
        }
    }

    // p = exp2(s); truncate-store to LDS with zero VALU (d16_hi)
#pragma unroll
    for (int nt = 0; nt < 4; ++nt)
#pragma unroll
      for (int r = 0; r < 4; ++r) {
        float p = __builtin_amdgcn_exp2f(sc[nt][r]);
        int rq = w * 16 + quad * 4 + r;
        int t = nt * 16 + l16;
        int c = t >> 3;
        ds_write_hi16(&sP[rq * 64 + ((c ^ (rq & 7)) * 8 + (t & 7))], p);
      }

    // O += P V ; l += P * ones (2 k-steps)
#pragma unroll
    for (int kst = 0; kst < 2; ++kst) {
      int rq = w * 16 + l16;
      int cpa = (kst * 4 + quad) ^ (rq & 7);
      short8 ap = *(const short8*)(sP + rq * 64 + cpa * 8);
      acc_l = __builtin_amdgcn_mfma_f32_16x16x32_bf16(ap, bones, acc_l, 0, 0, 0);
#pragma unroll
      for (int nt = 0; nt < 4; ++nt) {
        int row = nt * 16 + l16;
        int cv = (kst * 4 + quad) ^ (row & 7);
        short8 bv = *(const short8*)(sv + row * 64 + cv * 8);
        acc_o[nt] = __builtin_amdgcn_mfma_f32_16x16x32_bf16(ap, bv, acc_o[nt], 0, 0, 0);
      }
    }
    pb ^= 1;
  }

  if (qi < 8) {
    // single chunk: normalize + write Y[(s*2+b)][h*64+d] bf16
    const int b = bh / NHEADS, h = bh % NHEADS;
#pragma unroll
    for (int r = 0; r < 4; ++r) {
      float rl = __builtin_amdgcn_rcpf(acc_l[r]);
      int srow = q0 + w * 16 + quad * 4 + r;
#pragma unroll
      for (int nt = 0; nt < 4; ++nt)
        Y[(srow * 2 + b) * DMODEL + h * 64 + nt * 16 + l16] = cvtbf(acc_o[nt][r] * rl);
    }
  } else {
    // write unnormalized partial (O, l) f32
    const int slot = bh * 72 + PBASE[qi] + (ts >> 3);
    float* Ob = Of + (size_t)slot * 4096;
#pragma unroll
    for (int r = 0; r < 4; ++r) {
      int row = w * 16 + quad * 4 + r;
#pragma unroll
      for (int nt = 0; nt < 4; ++nt)
        Ob[row * 64 + nt * 16 + l16] = acc_o[nt][r];
      if (l16 == 0) lf[slot * 64 + row] = acc_l[r];
    }
  }
}

// ---------------- kernel 4b: merge 2-4 partials for qi>=8 ----------------
// grid 576 = 24 qi x 24 bh; 256 threads, 16 elems each
__global__ void attn_merge(const float* __restrict__ Of, const float* __restrict__ lf,
                           short* __restrict__ Y) {
  const int bh = blockIdx.x % 24, qi = 8 + blockIdx.x / 24;
  const int nch = (qi >> 3) + 1;             // 2,3,4
  const int base = bh * 72 + PBASE[qi];
  const float* O0 = Of + (size_t)base * 4096;
  const float* L0 = lf + base * 64;
  const int b = bh / NHEADS, h = bh % NHEADS;
  const int tid = threadIdx.x;
#pragma unroll
  for (int j = 0; j < 16; ++j) {
    int idx = j * 256 + tid;
    int row = idx >> 6, col = idx & 63;
    float o = 0.f, l = 0.f;
    for (int c = 0; c < nch; ++c) {
      o += O0[c * 4096 + idx];
      l += L0[c * 64 + row];
    }
    float v = o * __builtin_amdgcn_rcpf(l);
    int srow = qi * 64 + row;
    Y[(srow * 2 + b) * DMODEL + h * 64 + col] = cvtbf(v);
  }
}

// ---------------- kernel 5: output projection (f32 out + bias) ----------------
__global__ __launch_bounds__(256, 4) void oproj_gemm(
    const short* __restrict__ A, const short* __restrict__ Bt,
    const float* __restrict__ bo, float* __restrict__ out) {
  __shared__ short sA[64 * 64];
  __shared__ short sB[64 * 64];
  f32x4 acc[2][2];
  const f32x4 z4 = {0.f, 0.f, 0.f, 0.f};
#pragma unroll
  for (int mt = 0; mt < 2; ++mt)
#pragma unroll
    for (int nt = 0; nt < 2; ++nt) acc[mt][nt] = z4;

  const int bm = blockIdx.x, bn = blockIdx.y;
  gemm_core64<64>(A, Bt, sA, sB, bm, bn, acc);

  const int tid = threadIdx.x;
  const int w = tid >> 6, lane = tid & 63;
  const int quad = lane >> 4, l16 = lane & 15;
  const int wm = (w & 1) * 32, wn = (w >> 1) * 32;

#pragma unroll
  for (int nt = 0; nt < 2; ++nt) {
    int n = bn * 64 + wn + nt * 16 + l16;
    float bval = bo[n];
#pragma unroll
    for (int mt = 0; mt < 2; ++mt) {
      int rowb = wm + mt * 16 + quad * 4;
#pragma unroll
      for (int r = 0; r < 4; ++r) {
        int m = bm * 64 + rowb + r;
        out[(size_t)m * 768 + n] = acc[mt][nt][r] + bval;
      }
    }
  }
}

extern "C" void kernel_launch(void* const* d_in, const int* in_sizes, int n_in,
                              void* d_out, int out_size, void* d_ws, size_t ws_size,
                              hipStream_t stream) {
  const float* x  = (const float*)d_in[0];
  const float* Wq = (const float*)d_in[1];
  const float* bq = (const float*)d_in[2];
  const float* Wk = (const float*)d_in[3];
  const float* bk = (const float*)d_in[4];
  const float* Wv = (const float*)d_in[5];
  const float* bv = (const float*)d_in[6];
  const float* Wo = (const float*)d_in[7];
  const float* bo = (const float*)d_in[8];
  float* out = (float*)d_out;

  short* ws  = (short*)d_ws;
  short* xb  = ws;                    // 3145728 shorts: x bf16 [4096][768]
  short* wt  = ws + 3145728;          // 1769472: [2304][768] Wq^T,Wk^T,Wv^T
  short* wot = ws + 4915200;          //  589824: Wo^T [768][768]
  short* qw  = ws + 5505024;          // 3145728: Q (pre-scaled) [b][h][s][64]
  short* kw  = ws + 8650752;          // 3145728: K [b][h][s][64]
  short* vw  = ws + 11796480;         // 3145728: V^T [b][h][64][s]
  short* yw  = ws + 14942208;         // 3145728: attn out [4096][768]
  float* Of  = (float*)(ws + 18087936); // 1728 slots x 4096 f32 partial O (28.3 MB)
  float* lf  = Of + 7077888;            // 1728 slots x 64 f32 partial l

  cvt_x_kernel<<<1536, 256, 0, stream>>>(x, xb);
  transpose_w_kernel<<<dim3(24, 24, 4), dim3(32, 8), 0, stream>>>(Wq, Wk, Wv, Wo, wt, wot);
  qkv_gemm<<<dim3(64, 18), 256, 0, stream>>>(xb, wt, bq, bk, bv, qw, kw, vw);
  attn_kernel<<<1920, 256, 0, stream>>>(qw, kw, vw, yw, Of, lf);
  attn_merge<<<576, 256, 0, stream>>>(Of, lf, yw);
  oproj_gemm<<<dim3(64, 12), 256, 0, stream>>>(yw, wot, bo, out);
}